// Round 3
// baseline (28202.927 us; speedup 1.0000x reference)
//
#include <hip/hip_runtime.h>

#define LL 1024
#define NBLK 256
#define NTHR 512

typedef __attribute__((ext_vector_type(8))) __bf16 bf16x8;
typedef __attribute__((ext_vector_type(4))) __bf16 bf16x4;
typedef __attribute__((ext_vector_type(16))) float f32x16;

// All inputs/outputs are FLOAT32 (per reference). MFMA core runs bf16 with f32
// accumulate; f32->bf16 conversion done by pre-kernels into these statics.
// (Rounds 1-2 NaN = reading f32 buffers as bf16 -> NaN bit patterns.)
__device__ __bf16 g_trg[128 * 1024 * 256];   // 64 MB
__device__ __bf16 g_wih[4096 * 256];         // 2 MB
__device__ __bf16 g_whh[4096 * 1024];        // 8 MB
__device__ __bf16 g_wout[256 * 1024];        // 0.5 MB
__device__ __bf16 g_ring[2 * 4 * 32768];     // [slot][group][kc(128)][m(32)][8], 512 KB
__device__ unsigned int g_cnt[256];          // 4 used, 256B stride

__device__ __forceinline__ float sigm(float x) { return 1.f / (1.f + __expf(-x)); }
__device__ __forceinline__ float tanh_(float x) {
  x = fminf(fmaxf(x, -15.f), 15.f);
  float e = __expf(2.f * x);
  return (e - 1.f) / (e + 1.f);
}

__global__ void zero_cnt() {
  if (threadIdx.x < 256) g_cnt[threadIdx.x] = 0u;
}

__global__ void cvt4(const float* __restrict__ s, __bf16* __restrict__ d, int n4) {
  int i = blockIdx.x * blockDim.x + threadIdx.x;
  if (i < n4) {
    float4 v = ((const float4*)s)[i];
    bf16x4 o;
    o[0] = (__bf16)v.x; o[1] = (__bf16)v.y; o[2] = (__bf16)v.z; o[3] = (__bf16)v.w;
    ((bf16x4*)d)[i] = o;
  }
}

// Persistent LSTM decoder.
// Grid: 256 blocks = P(4 batch groups of 32) x Q(64 col-blocks of 16 h-cols).
// Block: 512 threads = 8 waves = (ct: col-tile of 32 gate-cols) x (ks: K-split of 320).
// K-domain = 1280: [0,1024) = h @ w_hh^T, [1024,1280) = x @ w_ih^T (teacher forcing).
// Weights live in VGPRs for the whole kernel; h exchanged via 2-slot global ring.
__global__ __launch_bounds__(NTHR, 2) void lstm_persist(
    const float* __restrict__ b_ih, const float* __restrict__ b_hh,
    const float* __restrict__ b_out, float* __restrict__ out)
{
  const int tid = threadIdx.x;
  const int lane = tid & 63;
  const int w = tid >> 6;        // wave 0..7
  const int ks = w & 3;          // K-split id
  const int ct = w >> 2;         // col-tile id
  const int gid = blockIdx.x;
  const int p = gid >> 6;        // batch group 0..3
  const int q = gid & 63;        // col block 0..63
  const int m = lane & 31;
  const int khalf = (lane >> 5) << 3;   // 0 or 8

  __shared__ float zpart[4][32][64];    // K-split partials of z
  __shared__ float opart[8][32][4];     // K-split partials of out-proj

  // ---- B fragments (weights) -> registers, kept for whole kernel ----
  const int nloc = (ct << 5) + m;          // 0..63: block-local gate col
  const int gate = nloc >> 4;              // 0=i 1=f 2=g 3=o
  const int hcb  = (q << 4) + (nloc & 15); // h column
  const int grow = (gate << 10) + hcb;     // gate row in [0,4096)

  bf16x8 bmain[20];
  #pragma unroll
  for (int s = 0; s < 20; ++s) {
    int k = ks * 320 + s * 16 + khalf;
    const __bf16* src = (k < 1024) ? (g_whh + grow * 1024 + k)
                                   : (g_wih + grow * 256 + (k - 1024));
    bmain[s] = *(const bf16x8*)src;
  }
  bf16x8 bo[8];
  #pragma unroll
  for (int s = 0; s < 8; ++s) {
    int k = (w << 7) + s * 16 + khalf;
    bf16x8 v;
    #pragma unroll
    for (int e = 0; e < 8; ++e) v[e] = (__bf16)0.f;
    if (m < 4) v = *(const bf16x8*)(g_wout + ((q << 2) + m) * 1024 + k);
    bo[s] = v;
  }

  // ---- elementwise role: thread <-> (batch row em, h-col ej) ----
  const int em = tid >> 4;             // 0..31
  const int ej = tid & 15;             // 0..15
  const int hcol = (q << 4) + ej;
  float bias0 = b_ih[hcol]        + b_hh[hcol];
  float bias1 = b_ih[1024 + hcol] + b_hh[1024 + hcol];
  float bias2 = b_ih[2048 + hcol] + b_hh[2048 + hcol];
  float bias3 = b_ih[3072 + hcol] + b_hh[3072 + hcol];
  float ob = 0.f;
  if (tid < 128) ob = b_out[(q << 2) + (tid & 3)];

  float cst = 0.f;
  f32x16 accm, acco;
  #pragma unroll
  for (int r = 0; r < 16; ++r) { accm[r] = 0.f; acco[r] = 0.f; }

  unsigned int* myc = g_cnt + (p << 6);  // per-group counter

  #pragma unroll 1
  for (int t = 0; t <= LL; ++t) {
    // ---- wait for h_{t-1} from all 64 blocks of this group ----
    if (t > 0) {
      if (tid == 0) {
        unsigned tgt = (unsigned)t << 6;
        int spins = 0;
        while (__hip_atomic_load(myc, __ATOMIC_RELAXED, __HIP_MEMORY_SCOPE_AGENT) < tgt) {
          __builtin_amdgcn_s_sleep(2);
          if (++spins > 30000) break;   // safety bailout
        }
      }
      __syncthreads();
      __builtin_amdgcn_fence(__ATOMIC_ACQUIRE, "agent");
    }
    const __bf16* rrd = g_ring + (((t + 1) & 1) << 17) + (p << 15);  // slot (t-1)&1

    // ---- recurrent + input GEMM: z = [h_{t-1} | x_t] @ [w_hh | w_ih]^T ----
    if (t < LL) {
      #pragma unroll
      for (int s = 0; s < 20; ++s) {
        int k0 = ks * 320 + s * 16;
        if (t == 0 && k0 < 1024) continue;   // h_{-1} = 0
        bf16x8 a;
        if (k0 < 1024) {
          a = *(const bf16x8*)(rrd + (k0 << 5) + (khalf << 5) + (m << 3));
        } else {
          int tx = (t == 0) ? 0 : (t - 1);   // teacher forcing shift
          a = *(const bf16x8*)(g_trg + (((size_t)(((p << 5) + m) << 10) + tx) << 8)
                               + (k0 - 1024) + khalf);
        }
        accm = __builtin_amdgcn_mfma_f32_32x32x16_bf16(a, bmain[s], accm, 0, 0, 0);
      }
    }
    // ---- fused output projection of h_{t-1} ----
    if (t > 0) {
      #pragma unroll
      for (int s = 0; s < 8; ++s) {
        int k0 = (w << 7) + s * 16;
        bf16x8 a = *(const bf16x8*)(rrd + (k0 << 5) + (khalf << 5) + (m << 3));
        acco = __builtin_amdgcn_mfma_f32_32x32x16_bf16(a, bo[s], acco, 0, 0, 0);
      }
    }
    // ---- dump partials to LDS (C/D: col=lane&31, row=(reg&3)+8*(reg>>2)+4*(lane>>5)) ----
    if (t < LL) {
      #pragma unroll
      for (int r = 0; r < 16; ++r) {
        int row = (r & 3) + ((r >> 2) << 3) + ((lane >> 5) << 2);
        zpart[ks][row][(ct << 5) + m] = accm[r];
        accm[r] = 0.f;
      }
    }
    if (t > 0) {
      #pragma unroll
      for (int r = 0; r < 16; ++r) {
        int row = (r & 3) + ((r >> 2) << 3) + ((lane >> 5) << 2);
        if (m < 4) opart[w][row][m] = acco[r];
        acco[r] = 0.f;
      }
    }
    __syncthreads();

    // ---- gates + state update; publish h_t to ring ----
    if (t < LL) {
      float zi = zpart[0][em][ej] + zpart[1][em][ej] + zpart[2][em][ej] + zpart[3][em][ej] + bias0;
      float zf = zpart[0][em][16+ej] + zpart[1][em][16+ej] + zpart[2][em][16+ej] + zpart[3][em][16+ej] + bias1;
      float zg = zpart[0][em][32+ej] + zpart[1][em][32+ej] + zpart[2][em][32+ej] + zpart[3][em][32+ej] + bias2;
      float zo = zpart[0][em][48+ej] + zpart[1][em][48+ej] + zpart[2][em][48+ej] + zpart[3][em][48+ej] + bias3;
      cst = sigm(zf) * cst + sigm(zi) * tanh_(zg);
      float h = sigm(zo) * tanh_(cst);
      __bf16* wr = g_ring + ((t & 1) << 17) + (p << 15);
      wr[((hcol >> 3) << 8) + (em << 3) + (hcol & 7)] = (__bf16)h;
    }
    // ---- reduce + write out[t-1] (f32, [B,L,O]) ----
    if (t > 0 && tid < 128) {
      int mm = tid >> 2, n = tid & 3;
      float s = ob;
      #pragma unroll
      for (int ww = 0; ww < 8; ++ww) s += opart[ww][mm][n];
      out[(((size_t)(((p << 5) + mm) << 10) + (t - 1)) << 8) + (q << 2) + n] = s;
    }
    // ---- arrive: release h_t ----
    if (t < LL) {
      __syncthreads();   // drains stores before release
      if (tid == 0)
        __hip_atomic_fetch_add(myc, 1u, __ATOMIC_RELEASE, __HIP_MEMORY_SCOPE_AGENT);
    }
  }
}

extern "C" void kernel_launch(void* const* d_in, const int* in_sizes, int n_in,
                              void* d_out, int out_size, void* d_ws, size_t ws_size,
                              hipStream_t stream) {
  const float* trg   = (const float*)d_in[0];
  const float* w_ih  = (const float*)d_in[1];
  const float* w_hh  = (const float*)d_in[2];
  const float* b_ih  = (const float*)d_in[3];
  const float* b_hh  = (const float*)d_in[4];
  const float* w_out = (const float*)d_in[5];
  const float* b_out = (const float*)d_in[6];

  __bf16 *p_trg, *p_wih, *p_whh, *p_wout;
  hipGetSymbolAddress((void**)&p_trg,  HIP_SYMBOL(g_trg));
  hipGetSymbolAddress((void**)&p_wih,  HIP_SYMBOL(g_wih));
  hipGetSymbolAddress((void**)&p_whh,  HIP_SYMBOL(g_whh));
  hipGetSymbolAddress((void**)&p_wout, HIP_SYMBOL(g_wout));

  // f32 -> bf16 conversions (vectorized, grid-stride free: exact division)
  cvt4<<<dim3(33554432 / 4 / 256), dim3(256), 0, stream>>>(trg,   p_trg,  33554432 / 4);
  cvt4<<<dim3(1048576  / 4 / 256), dim3(256), 0, stream>>>(w_ih,  p_wih,  1048576  / 4);
  cvt4<<<dim3(4194304  / 4 / 256), dim3(256), 0, stream>>>(w_hh,  p_whh,  4194304  / 4);
  cvt4<<<dim3(262144   / 4 / 256), dim3(256), 0, stream>>>(w_out, p_wout, 262144   / 4);
  zero_cnt<<<dim3(1), dim3(256), 0, stream>>>();

  lstm_persist<<<dim3(NBLK), dim3(NTHR), 0, stream>>>(b_ih, b_hh, b_out, (float*)d_out);
}

// Round 4
// 5872.776 us; speedup vs baseline: 4.8023x; 4.8023x over previous
//
#include <hip/hip_runtime.h>

#define LL 1024
#define NBLK 256
#define NTHR 512

typedef __attribute__((ext_vector_type(8))) __bf16 bf16x8;
typedef __attribute__((ext_vector_type(4))) __bf16 bf16x4;
typedef __attribute__((ext_vector_type(16))) float f32x16;

// All inputs/outputs are FLOAT32. MFMA core runs bf16 (f32 accumulate).
__device__ __bf16 g_trg[128 * 1024 * 256];     // 64 MB
__device__ __bf16 g_wih[4096 * 256];           // 2 MB
__device__ __bf16 g_whh[4096 * 1024];          // 8 MB
__device__ __bf16 g_wout[256 * 1024];          // 0.5 MB
// Write-once h ring: [t(1024)][group(4)][kc(128)][m(32)][8] bf16 = 268 MB.
// Fresh addresses every step -> readers use plain cached loads, no invalidates.
// Cross-replay staleness is value-identical (deterministic) + entry fence.
__device__ __bf16 g_ring[(size_t)1024 * 4 * 32768];
__device__ unsigned int g_cnt[256];            // 4 used, 256B stride

__device__ __forceinline__ float sigm(float x) { return 1.f / (1.f + __expf(-x)); }
__device__ __forceinline__ float tanh_(float x) {
  x = fminf(fmaxf(x, -15.f), 15.f);
  float e = __expf(2.f * x);
  return (e - 1.f) / (e + 1.f);
}

__global__ void zero_cnt() {
  if (threadIdx.x < 256) g_cnt[threadIdx.x] = 0u;
}

__global__ void cvt4(const float* __restrict__ s, __bf16* __restrict__ d, int n4) {
  int i = blockIdx.x * blockDim.x + threadIdx.x;
  if (i < n4) {
    float4 v = ((const float4*)s)[i];
    bf16x4 o;
    o[0] = (__bf16)v.x; o[1] = (__bf16)v.y; o[2] = (__bf16)v.z; o[3] = (__bf16)v.w;
    ((bf16x4*)d)[i] = o;
  }
}

// Persistent LSTM decoder. Grid: 256 blocks = P(4 batch groups of 32 rows) x
// Q(64 col-blocks of 16 h-cols). Block: 8 waves = ct(2 col-tiles) x ks(4 K-splits).
// Wave ks K-slice: h-k [ks*256,(ks+1)*256) + x-k [1024+ks*64, 1024+(ks+1)*64).
// Fence-free exchange: write-through (sc1) h stores + relaxed agent counter;
// cached reads of never-reused ring addresses.
__global__ __launch_bounds__(NTHR, 2) void lstm_persist(
    const float* __restrict__ b_ih, const float* __restrict__ b_hh,
    const float* __restrict__ b_out, float* __restrict__ out)
{
  const int tid = threadIdx.x;
  const int lane = tid & 63;
  const int w = tid >> 6;        // wave 0..7
  const int ks = w & 3;          // K-split id
  const int ct = w >> 2;         // col-tile id
  const int gid = blockIdx.x;
  const int p = gid >> 6;        // batch group 0..3
  const int q = gid & 63;        // col block 0..63
  const int m = lane & 31;
  const int khalf = (lane >> 5) << 3;   // 0 or 8

  __shared__ float zpart[4][32][64];                    // K-split partials of z
  __shared__ float opart[8][32][4];                     // K-split partials of out-proj
  __shared__ __align__(16) unsigned short hstage[512];  // packed h_t (ring layout)

  // One-time invalidate of stale L1/L2 lines from a previous replay.
  __builtin_amdgcn_fence(__ATOMIC_ACQUIRE, "agent");

  // ---- B fragments (weights) -> registers, kept for whole kernel ----
  const int nloc = (ct << 5) + m;          // 0..63: block-local gate col
  const int gate = nloc >> 4;              // 0=i 1=f 2=g 3=o
  const int hcb  = (q << 4) + (nloc & 15); // h column
  const int grow = (gate << 10) + hcb;     // gate row in [0,4096)

  bf16x8 bmain[20];
  #pragma unroll
  for (int s = 0; s < 16; ++s) {           // recurrent slice
    int k = (ks << 8) + (s << 4) + khalf;
    bmain[s] = *(const bf16x8*)(g_whh + grow * 1024 + k);
  }
  #pragma unroll
  for (int s = 0; s < 4; ++s) {            // input slice
    int k = (ks << 6) + (s << 4) + khalf;
    bmain[16 + s] = *(const bf16x8*)(g_wih + grow * 256 + k);
  }
  bf16x8 bo[8];
  #pragma unroll
  for (int s = 0; s < 8; ++s) {
    int k = (w << 7) + s * 16 + khalf;
    bf16x8 v;
    #pragma unroll
    for (int e = 0; e < 8; ++e) v[e] = (__bf16)0.f;
    if (m < 4) v = *(const bf16x8*)(g_wout + ((q << 2) + m) * 1024 + k);
    bo[s] = v;
  }

  // ---- elementwise role: thread <-> (batch row em, h-col ej) ----
  const int em = tid >> 4;             // 0..31
  const int ej = tid & 15;             // 0..15
  const int hcol = (q << 4) + ej;
  float bias0 = b_ih[hcol]        + b_hh[hcol];
  float bias1 = b_ih[1024 + hcol] + b_hh[1024 + hcol];
  float bias2 = b_ih[2048 + hcol] + b_hh[2048 + hcol];
  float bias3 = b_ih[3072 + hcol] + b_hh[3072 + hcol];
  float ob = 0.f;
  if (tid < 128) ob = b_out[(q << 2) + (tid & 3)];

  float cst = 0.f;
  f32x16 accm, acco;
  #pragma unroll
  for (int r = 0; r < 16; ++r) { accm[r] = 0.f; acco[r] = 0.f; }

  unsigned int* myc = g_cnt + (p << 6);
  const size_t trgbase = (size_t)(((p << 5) + m) << 10);

  #pragma unroll 1
  for (int t = 0; t <= LL; ++t) {
    // ---- pre-wait: x-projection MFMAs (h-independent) ----
    if (t < LL) {
      int tx = (t == 0) ? 0 : (t - 1);   // teacher forcing shift
      const __bf16* trow = g_trg + ((trgbase + tx) << 8);
      #pragma unroll
      for (int s = 0; s < 4; ++s) {
        bf16x8 a = *(const bf16x8*)(trow + (ks << 6) + (s << 4) + khalf);
        accm = __builtin_amdgcn_mfma_f32_32x32x16_bf16(a, bmain[16 + s], accm, 0, 0, 0);
      }
    }
    // ---- barrier: wait for h_{t-1} from all 64 blocks of this group ----
    if (t > 0) {
      if (tid == 0) {
        unsigned tgt = (unsigned)t << 6;
        int spins = 0;
        while (__hip_atomic_load(myc, __ATOMIC_RELAXED, __HIP_MEMORY_SCOPE_AGENT) < tgt) {
          __builtin_amdgcn_s_sleep(2);
          if (++spins > 30000) break;   // safety bailout
        }
      }
      __syncthreads();   // (A)
    }
    const __bf16* rrd = g_ring + (size_t)(t > 0 ? t - 1 : 0) * 131072 + (p << 15);

    // ---- recurrent GEMM: z += h_{t-1} @ w_hh^T (cached ring loads) ----
    if (t > 0 && t < LL) {
      #pragma unroll
      for (int s = 0; s < 16; ++s) {
        int k0 = (ks << 8) + (s << 4);
        bf16x8 a = *(const bf16x8*)(rrd + (k0 << 5) + (khalf << 5) + (m << 3));
        accm = __builtin_amdgcn_mfma_f32_32x32x16_bf16(a, bmain[s], accm, 0, 0, 0);
      }
    }
    // ---- dump K-split partials (C/D: col=lane&31, row=(r&3)+8*(r>>2)+4*(lane>>5)) ----
    if (t < LL) {
      #pragma unroll
      for (int r = 0; r < 16; ++r) {
        int row = (r & 3) + ((r >> 2) << 3) + ((lane >> 5) << 2);
        zpart[ks][row][(ct << 5) + m] = accm[r];
        accm[r] = 0.f;
      }
    }
    __syncthreads();     // (B)

    // ---- gates + state update; pack h_t into LDS ----
    if (t < LL) {
      float zi = zpart[0][em][ej] + zpart[1][em][ej] + zpart[2][em][ej] + zpart[3][em][ej] + bias0;
      float zf = zpart[0][em][16+ej] + zpart[1][em][16+ej] + zpart[2][em][16+ej] + zpart[3][em][16+ej] + bias1;
      float zg = zpart[0][em][32+ej] + zpart[1][em][32+ej] + zpart[2][em][32+ej] + zpart[3][em][32+ej] + bias2;
      float zo = zpart[0][em][48+ej] + zpart[1][em][48+ej] + zpart[2][em][48+ej] + zpart[3][em][48+ej] + bias3;
      cst = sigm(zf) * cst + sigm(zi) * tanh_(zg);
      float h = sigm(zo) * tanh_(cst);
      __bf16 hb = (__bf16)h;
      hstage[((ej >> 3) << 8) | (em << 3) | (ej & 7)] = *(unsigned short*)&hb;
    }
    __syncthreads();     // (C)

    // ---- publish h_t: wave0 write-through stores + relaxed release add ----
    if (t < LL) {
      if (tid < 64) {
        unsigned long long* dst =
            (unsigned long long*)(g_ring + (size_t)t * 131072 + (p << 15) + (q << 9)) + (tid << 1);
        unsigned long long v0 = *(const unsigned long long*)&hstage[tid << 3];
        unsigned long long v1 = *(const unsigned long long*)&hstage[(tid << 3) + 4];
        __hip_atomic_store(dst,     v0, __ATOMIC_RELAXED, __HIP_MEMORY_SCOPE_AGENT);
        __hip_atomic_store(dst + 1, v1, __ATOMIC_RELAXED, __HIP_MEMORY_SCOPE_AGENT);
      }
      if (tid == 0) {
        asm volatile("s_waitcnt vmcnt(0)" ::: "memory");  // stores at coherence point
        __hip_atomic_fetch_add(myc, 1u, __ATOMIC_RELAXED, __HIP_MEMORY_SCOPE_AGENT);
      }
    }

    // ---- off-critical-path: out-projection of h_{t-1} + write out[t-1] ----
    if (t > 0) {
      #pragma unroll
      for (int s = 0; s < 8; ++s) {
        int k0 = (w << 7) + s * 16;
        bf16x8 a = *(const bf16x8*)(rrd + (k0 << 5) + (khalf << 5) + (m << 3));
        acco = __builtin_amdgcn_mfma_f32_32x32x16_bf16(a, bo[s], acco, 0, 0, 0);
      }
      #pragma unroll
      for (int r = 0; r < 16; ++r) {
        int row = (r & 3) + ((r >> 2) << 3) + ((lane >> 5) << 2);
        if (m < 4) opart[w][row][m] = acco[r];
        acco[r] = 0.f;
      }
      __syncthreads();   // (D)
      if (tid < 128) {
        int mm = tid >> 2, n = tid & 3;
        float s = ob;
        #pragma unroll
        for (int ww = 0; ww < 8; ++ww) s += opart[ww][mm][n];
        out[(((size_t)(((p << 5) + mm) << 10) + (t - 1)) << 8) + (q << 2) + n] = s;
      }
    }
  }
}

extern "C" void kernel_launch(void* const* d_in, const int* in_sizes, int n_in,
                              void* d_out, int out_size, void* d_ws, size_t ws_size,
                              hipStream_t stream) {
  const float* trg   = (const float*)d_in[0];
  const float* w_ih  = (const float*)d_in[1];
  const float* w_hh  = (const float*)d_in[2];
  const float* b_ih  = (const float*)d_in[3];
  const float* b_hh  = (const float*)d_in[4];
  const float* w_out = (const float*)d_in[5];
  const float* b_out = (const float*)d_in[6];

  __bf16 *p_trg, *p_wih, *p_whh, *p_wout;
  hipGetSymbolAddress((void**)&p_trg,  HIP_SYMBOL(g_trg));
  hipGetSymbolAddress((void**)&p_wih,  HIP_SYMBOL(g_wih));
  hipGetSymbolAddress((void**)&p_whh,  HIP_SYMBOL(g_whh));
  hipGetSymbolAddress((void**)&p_wout, HIP_SYMBOL(g_wout));

  cvt4<<<dim3(33554432 / 4 / 256), dim3(256), 0, stream>>>(trg,   p_trg,  33554432 / 4);
  cvt4<<<dim3(1048576  / 4 / 256), dim3(256), 0, stream>>>(w_ih,  p_wih,  1048576  / 4);
  cvt4<<<dim3(4194304  / 4 / 256), dim3(256), 0, stream>>>(w_hh,  p_whh,  4194304  / 4);
  cvt4<<<dim3(262144   / 4 / 256), dim3(256), 0, stream>>>(w_out, p_wout, 262144   / 4);
  zero_cnt<<<dim3(1), dim3(256), 0, stream>>>();

  lstm_persist<<<dim3(NBLK), dim3(NTHR), 0, stream>>>(b_ih, b_hh, b_out, (float*)d_out);
}